// Round 6
// baseline (196.299 us; speedup 1.0000x reference)
//
#include <hip/hip_runtime.h>

// Gammatone filterbank, EXACT affine state-passing (v6).
// Evidence v1-v5: time = max(~80cyc x worst-SIMD samples, FLOOR ~72us);
// warm-up-based versions all sit on the floor. This version removes the
// warm-up entirely (3x less issued work, exact math) to either break the
// floor or prove it structural.
//
// Recurrence s[t] = M s[t-1] + (1,1,1,1)x[t], M = c*L1 (unit lower-tri of
// ones, c = complex pole). Over a chunk of L: s_end = M^L s_start + delta,
// M^L = c^L * L1^L, (L1^L)[j][i] = C(L-1+d, d), d=j-i. Three launches:
//  P1: each (half,chunk,batch) runs its chunk from ZERO state, stores the
//      4 complex end-states (delta) to ws.                    [256 smp/wave]
//  P2: 1024 threads: per (b,c) chain s_in[k+1] = M^L s_in[k] + delta[k]
//      over 125 chunks (serial, prefetch-2), overwrite ws with s_in.
//  P3: each chunk reruns from its EXACT start state, stores outputs.
//                                                             [256 smp/wave]
// Stage-skewed inner loop kept from v2: at iteration i regs hold
// s1=y1[i+2], s2=y2[i+1], s3=y3[i], s4=y4[i-1]; 4 independent 2-FMA chains.

typedef float f32x2 __attribute__((ext_vector_type(2)));

#define B_N   8
#define T_LEN 32000
#define C_CH  128
#define L_CHK 256
#define NKC   125          // T_LEN / L_CHK

// One skewed pipeline step, consuming x[i+3] (see v2 derivation).
#define PSTEP(XR) do {                               \
    const f32x2 xin = {(XR), 0.f};                   \
    const f32x2 t4 = crr * s4 + s3;                  \
    const f32x2 t3 = crr * s3 + s2;                  \
    const f32x2 t2 = crr * s2 + s1;                  \
    const f32x2 t1 = crr * s1 + xin;                 \
    s4 = cni * s4.yx + t4;                           \
    s3 = cni * s3.yx + t3;                           \
    s2 = cni * s2.yx + t2;                           \
    s1 = cni * s1.yx + t1;                           \
} while (0)

// DST = c * S + ADD (complex, via the same 2-FMA pattern)
#define CMADD(DST, S, ADD) do {                      \
    const f32x2 _t = crr * (S) + (ADD);              \
    DST = cni * (S).yx + _t;                         \
} while (0)

__device__ inline f32x2 cmul(f32x2 a, f32x2 s) {
    return (f32x2){a.x * s.x - a.y * s.y, a.x * s.y + a.y * s.x};
}

template<int PHASE>
__global__ __launch_bounds__(64) void gt_phase(
    const float* __restrict__ x, const float* __restrict__ cre,
    const float* __restrict__ cim, const float* __restrict__ fac,
    float* __restrict__ out, float* __restrict__ ws)
{
    __shared__ __align__(16) float xs[L_CHK + 16];
    const int g  = blockIdx.x;            // channel half
    const int k  = blockIdx.y;            // time chunk
    const int b  = blockIdx.z;            // batch
    const int c  = g * 64 + threadIdx.x;
    const int t0 = k * L_CHK;
    // Stage L real samples + up to 3 lookahead (pollutes only dead/captured
    // state); zero-fill 8 tail slots so reads past T are defined.
    const int n_avail = (T_LEN - t0 < L_CHK + 3) ? (T_LEN - t0) : (L_CHK + 3);

    const float* xb = x + (size_t)b * T_LEN + t0;
    for (int i = threadIdx.x; i < n_avail; i += 64) xs[i + 1] = xb[i];
    if (threadIdx.x < 8) xs[n_avail + 1 + threadIdx.x] = 0.f;

    const float cr = cre[c], ci = cim[c];
    const f32x2 crr = {cr, cr};
    const f32x2 cni = {-ci, ci};

    // Chunk-start state sigma = y_j[-1]: zero for P1, exact (from P2) for P3.
    f32x2 sg1 = {0.f,0.f}, sg2 = {0.f,0.f}, sg3 = {0.f,0.f}, sg4 = {0.f,0.f};
    float* wp = ws + (((size_t)k * 8 + b) * 128 + c) * 8;
    if constexpr (PHASE == 3) {
        const float4 A  = *(const float4*)wp;
        const float4 Bv = *(const float4*)(wp + 4);
        sg1 = (f32x2){A.x,  A.y};  sg2 = (f32x2){A.z,  A.w};
        sg3 = (f32x2){Bv.x, Bv.y}; sg4 = (f32x2){Bv.z, Bv.w};
    }
    __syncthreads();

    // Pipeline fill from sigma (x0..x2 = xs[1..3]):
    //   y1[0]=c*sg1+x0; y1[1]=c*y1[0]+x1; s1=y1[2]=c*y1[1]+x2
    //   y2[0]=c*sg2+y1[0]; s2=y2[1]=c*y2[0]+y1[1]; s3=y3[0]=c*sg3+y2[0]
    //   s4=y4[-1]=sg4
    const f32x2 x0v = {xs[1], 0.f}, x1v = {xs[2], 0.f}, x2v = {xs[3], 0.f};
    f32x2 y10, y11, y20, s1, s2, s3, s4;
    CMADD(y10, sg1, x0v);
    CMADD(y11, y10, x1v);
    CMADD(s1,  y11, x2v);
    CMADD(y20, sg2, y10);
    CMADD(s2,  y20, y11);
    CMADD(s3,  sg3, y20);
    s4 = sg4;

    float4 cur = *(const float4*)&xs[4];
    if constexpr (PHASE == 1) {
        // 63 quads, then a capture quad: after PSTEP at step i, the reg
        // holding y_j[L-1] is s1 at i=L-4, s2 at L-3, s3 at L-2, s4 at L-1
        // (skew overshoot beyond L only pollutes already-captured regs).
        for (int i = 0; i < L_CHK - 4; i += 4) {
            const float4 nxt = *(const float4*)&xs[i + 8];
            PSTEP(cur.x); PSTEP(cur.y); PSTEP(cur.z); PSTEP(cur.w);
            cur = nxt;
        }
        f32x2 sv1, sv2, sv3, sv4;
        PSTEP(cur.x); sv1 = s1;     // y1[L-1]
        PSTEP(cur.y); sv2 = s2;     // y2[L-1]
        PSTEP(cur.z); sv3 = s3;     // y3[L-1]
        PSTEP(cur.w); sv4 = s4;     // y4[L-1]
        *(float4*)wp       = (float4){sv1.x, sv1.y, sv2.x, sv2.y};
        *(float4*)(wp + 4) = (float4){sv3.x, sv3.y, sv4.x, sv4.y};
    } else {
        const float f = fac[c];
        float* op = out + ((size_t)b * T_LEN + t0) * C_CH + c;
        for (int i = 0; i < L_CHK; i += 4) {
            const float4 nxt = *(const float4*)&xs[i + 8];
            PSTEP(cur.x); op[0 * C_CH] = s4.x * f;
            PSTEP(cur.y); op[1 * C_CH] = s4.x * f;
            PSTEP(cur.z); op[2 * C_CH] = s4.x * f;
            PSTEP(cur.w); op[3 * C_CH] = s4.x * f;
            op += 4 * (size_t)C_CH;
            cur = nxt;
        }
    }
}

__global__ __launch_bounds__(64) void gt_chain(
    const float* __restrict__ cre, const float* __restrict__ cim,
    float* __restrict__ ws)
{
    const int b = blockIdx.x >> 1;
    const int c = (blockIdx.x & 1) * 64 + threadIdx.x;
    const float cr = cre[c], ci = cim[c];
    // c^256 by 8 complex squarings (underflows to 0 for high channels: the
    // cross-chunk memory genuinely vanishes there).
    float pr = cr, pi = ci;
    #pragma unroll
    for (int q = 0; q < 8; ++q) {
        const float nr = pr * pr - pi * pi, ni = 2.f * pr * pi;
        pr = nr; pi = ni;
    }
    // M^L entries by diagonal d: m_d = c^L * C(L-1+d, d), L=256.
    const f32x2 m0 = {pr, pi};
    const f32x2 m1 = {pr * 256.f,     pi * 256.f};
    const f32x2 m2 = {pr * 32896.f,   pi * 32896.f};
    const f32x2 m3 = {pr * 2829056.f, pi * 2829056.f};

    float* p = ws + ((size_t)b * 128 + c) * 8;    // slot (k=0, b, c)
    const size_t KS = (size_t)8 * 128 * 8;        // floats per k
    // prefetch-2 on delta[k]
    float4 A0 = *(const float4*)p,          B0 = *(const float4*)(p + 4);
    float4 A1 = *(const float4*)(p + KS),   B1 = *(const float4*)(p + KS + 4);
    f32x2 s1 = {0,0}, s2 = {0,0}, s3 = {0,0}, s4 = {0,0};  // s_in[0] = 0
    for (int k = 0; k < NKC; ++k) {
        const f32x2 d1 = {A0.x, A0.y}, d2 = {A0.z, A0.w};
        const f32x2 d3 = {B0.x, B0.y}, d4 = {B0.z, B0.w};
        // overwrite slot k with s_in[k] (delta[k] already in registers)
        *(float4*)p       = (float4){s1.x, s1.y, s2.x, s2.y};
        *(float4*)(p + 4) = (float4){s3.x, s3.y, s4.x, s4.y};
        A0 = A1; B0 = B1;
        if (k < NKC - 2) {
            A1 = *(const float4*)(p + 2 * KS);
            B1 = *(const float4*)(p + 2 * KS + 4);
        }
        // s_in[k+1] = M^L s_in[k] + delta[k]  (lower-tri Toeplitz matvec)
        const f32x2 n4 = cmul(m0,s4) + cmul(m1,s3) + cmul(m2,s2) + cmul(m3,s1) + d4;
        const f32x2 n3 = cmul(m0,s3) + cmul(m1,s2) + cmul(m2,s1) + d3;
        const f32x2 n2 = cmul(m0,s2) + cmul(m1,s1) + d2;
        const f32x2 n1 = cmul(m0,s1) + d1;
        s1 = n1; s2 = n2; s3 = n3; s4 = n4;
        p += KS;
    }
}

extern "C" void kernel_launch(void* const* d_in, const int* in_sizes, int n_in,
                              void* d_out, int out_size, void* d_ws, size_t ws_size,
                              hipStream_t stream) {
    const float* x   = (const float*)d_in[0];
    const float* cre = (const float*)d_in[1];
    const float* cim = (const float*)d_in[2];
    const float* fac = (const float*)d_in[3];
    float* out = (float*)d_out;
    float* ws  = (float*)d_ws;   // needs 125*8*128*8*4 B = 4.1 MB

    gt_phase<1><<<dim3(2, NKC, B_N), 64, 0, stream>>>(x, cre, cim, fac, out, ws);
    gt_chain   <<<16, 64, 0, stream>>>(cre, cim, ws);
    gt_phase<3><<<dim3(2, NKC, B_N), 64, 0, stream>>>(x, cre, cim, fac, out, ws);
}

// Round 7
// 151.680 us; speedup vs baseline: 1.2942x; 1.2942x over previous
//
#include <hip/hip_runtime.h>

// Gammatone filterbank, truncated-history, stage-skewed packed-f32 loop.
// v7 = v2's single-dispatch structure (multi-dispatch costs ~20-30us each,
// proven by v6; makespan tuning below ~1500 smp is a no-op, proven by v5)
// with the inner loop's latency exposure attacked directly:
//  (a) 2-deep LDS prefetch: two float4 quads in flight; each ds_read_b128
//      is issued ~2 iterations (~100+ cyc) before first use, covering the
//      ~120 cyc LDS latency that 1-quad-ahead left ~40-70 cyc exposed
//      (unhideable at 1 wave/SIMD).
//  (b) #pragma unroll 2 on warm-up and output loops: halves loop-control
//      overhead per sample.
//  (c) warm-up constant 18 -> 14 (validated in v5: absmax stayed at the
//      0.00390625 harness floor): W0 1024 -> 872, makespan 1524 -> 1372.
// Stage skew kept: at iteration i regs hold s1=y1[i+2], s2=y2[i+1],
// s3=y3[i], s4=y4[i-1]; 4 independent 2-FMA chains per sample.

typedef float f32x2 __attribute__((ext_vector_type(2)));

#define B_N    8
#define T_LEN  32000
#define C_CH   128
#define L_CHK  500
#define NB     64          // T_LEN / L_CHK
#define W_MAX  1024

// One skewed pipeline step, consuming x[i+3]:
//   s4 <- y4[i]   = c*y4[i-1] + y3[i]
//   s3 <- y3[i+1] = c*y3[i]   + y2[i+1]
//   s2 <- y2[i+2] = c*y2[i+1] + y1[i+2]
//   s1 <- y1[i+3] = c*y1[i+2] + x[i+3]
// All t's read pre-update values; the 4 (t,s) pairs are independent.
#define PSTEP(XR) do {                               \
    const f32x2 xin = {(XR), 0.f};                   \
    const f32x2 t4 = crr * s4 + s3;                  \
    const f32x2 t3 = crr * s3 + s2;                  \
    const f32x2 t2 = crr * s2 + s1;                  \
    const f32x2 t1 = crr * s1 + xin;                 \
    s4 = cni * s4.yx + t4;                           \
    s3 = cni * s3.yx + t3;                           \
    s2 = cni * s2.yx + t2;                           \
    s1 = cni * s1.yx + t1;                           \
} while (0)

__global__ __launch_bounds__(64, 1) void gt_trunc(
    const float* __restrict__ x, const float* __restrict__ cre,
    const float* __restrict__ cim, const float* __restrict__ fac,
    float* __restrict__ out)
{
    __shared__ __align__(16) float xs[W_MAX + L_CHK + 16];
    const int g  = blockIdx.x;            // channel half (0: ch 0-63, 1: ch 64-127)
    const int k  = blockIdx.y;            // time chunk
    const int b  = blockIdx.z;            // batch
    const int c  = g * 64 + threadIdx.x;
    const int t0 = k * L_CHK;

    // Warm-up length from the largest-|c| channel of this half (channel g*64:
    // |c| decreases with channel index). A=14: truncation err ~3.6e-3 vs
    // the 4e-2 threshold (validated v5: absmax stays at harness floor).
    const float cr0 = cre[g * 64], ci0 = cim[g * 64];
    const float negln = -0.5f * __logf(cr0 * cr0 + ci0 * ci0);   // -ln|c|
    int W = (int)ceilf(14.0f / negln) + 2;
    W = (W + 3) & ~3;                      // multiple of 4 (float4 LDS reads)
    if (W > W_MAX) W = W_MAX;
    int start = t0 - W;
    if (start < 0) start = 0;              // early chunks: zero init is exact
    const int n  = t0 + L_CHK - start;     // staged samples (multiple of 4)
    const int nw = t0 - start;             // warm-up steps (multiple of 4)

    // Stage x[start .. t0+L) into LDS at xs[1..n] (shifted by 1 so the
    // skewed consumption index i+3 lands on 16B-aligned float4 quads),
    // coalesced. Zero-fill 12 tail slots: the 2-deep prefetch reads up to
    // xs[nw+511]; anything past n only feeds dead s1..s3 values but must
    // not be NaN garbage.
    const float* xb = x + (size_t)b * T_LEN + start;
    for (int i = threadIdx.x; i < n; i += 64) xs[i + 1] = xb[i];
    if (threadIdx.x < 12) xs[n + 1 + threadIdx.x] = 0.f;

    const float cr = cre[c], ci = cim[c], f = fac[c];
    const f32x2 crr = {cr, cr};
    const f32x2 cni = {-ci, ci};
    __syncthreads();

    // Pipeline fill in closed form from zero state (x0..x2 = xs[1..3]):
    //   s1 = y1[2], s2 = y2[1], s3 = y3[0], s4 = y4[-1] = 0.
    const f32x2 a0 = {xs[1], 0.f}, a1 = {xs[2], 0.f}, a2 = {xs[3], 0.f};
    f32x2 t, y11, s1, s2, s3, s4;
    t  = crr * a0  + a1;  y11 = cni * a0.yx  + t;   // y1[1]
    t  = crr * y11 + a2;  s1  = cni * y11.yx + t;   // y1[2]
    t  = crr * a0  + y11; s2  = cni * a0.yx  + t;   // y2[1]
    s3 = a0;                                         // y3[0] = x[0]
    s4 = (f32x2){0.f, 0.f};                          // y4[-1]

    // Warm-up (no stores). 2-deep software pipeline: q0 = xs[i+4..7],
    // q1 = xs[i+8..11]; the load of xs[i+12..15] is issued a full two
    // iterations (~100+ cyc of FMA work) before its first use.
    float4 q0 = *(const float4*)&xs[4];
    float4 q1 = *(const float4*)&xs[8];
    #pragma unroll 2
    for (int i = 0; i < nw; i += 4) {
        const float4 q2 = *(const float4*)&xs[i + 12];
        PSTEP(q0.x); PSTEP(q0.y); PSTEP(q0.z); PSTEP(q0.w);
        q0 = q1; q1 = q2;
    }
    // loop exit: q0 = xs[nw+4..7], q1 = xs[nw+8..11]

    // Output region: after the step at iteration i, s4 = y4[i]; store for
    // i >= nw. One coalesced 256 B wave-store per time step; gain applied
    // at store (filter is linear).
    float* op = out + ((size_t)b * T_LEN + t0) * C_CH + c;
    #pragma unroll 2
    for (int i = nw; i < nw + L_CHK; i += 4) {
        const float4 q2 = *(const float4*)&xs[i + 12];
        PSTEP(q0.x); op[0 * C_CH] = s4.x * f;
        PSTEP(q0.y); op[1 * C_CH] = s4.x * f;
        PSTEP(q0.z); op[2 * C_CH] = s4.x * f;
        PSTEP(q0.w); op[3 * C_CH] = s4.x * f;
        op += 4 * (size_t)C_CH;
        q0 = q1; q1 = q2;
    }
}

extern "C" void kernel_launch(void* const* d_in, const int* in_sizes, int n_in,
                              void* d_out, int out_size, void* d_ws, size_t ws_size,
                              hipStream_t stream) {
    const float* x   = (const float*)d_in[0];
    const float* cre = (const float*)d_in[1];
    const float* cim = (const float*)d_in[2];
    const float* fac = (const float*)d_in[3];
    float* out = (float*)d_out;

    gt_trunc<<<dim3(2, NB, B_N), 64, 0, stream>>>(x, cre, cim, fac, out);
}